// Round 17
// baseline (175.298 us; speedup 1.0000x reference)
//
#include <hip/hip_runtime.h>
#include <stdint.h>

typedef _Float16 f16;
typedef _Float16 f16x2 __attribute__((ext_vector_type(2)));
typedef _Float16 f16x8 __attribute__((ext_vector_type(8)));
typedef float f32x4 __attribute__((ext_vector_type(4)));
typedef float f32x16 __attribute__((ext_vector_type(16)));
typedef uint32_t u32x4 __attribute__((ext_vector_type(4)));

#define B_   4
#define S_   2048
#define E_   1024
#define H_   16
#define HD_  64
#define BH_  (B_ * H_)

template <int N> struct IC { static constexpr int v = N; };

// ---------------------------------------------------------------- helpers
__device__ __forceinline__ void async_lds16(const void* g, void* l) {
    __builtin_amdgcn_global_load_lds(
        (__attribute__((address_space(1))) void*)(uintptr_t)g,
        (__attribute__((address_space(3))) void*)(uint32_t)(uintptr_t)l,
        16, 0, 0);
}

// ---------------------------------------------------------------- fused fp32 -> fp16 (x, w1, w2)
__global__ __launch_bounds__(256)
void cvt3(const float* __restrict__ x, const float* __restrict__ w1,
          const float* __restrict__ w2, f16* __restrict__ xb,
          f16* __restrict__ w1b, f16* __restrict__ w2b)
{
    const long i = (long)blockIdx.x * 256 + threadIdx.x;   // 8-elem chunk id
    const float* src; f16* dst; long j;
    if (i < 1048576)      { src = x;  dst = xb;  j = i; }
    else if (i < 1441792) { src = w1; dst = w1b; j = i - 1048576; }
    else                  { src = w2; dst = w2b; j = i - 1441792; }
    const float4* p = (const float4*)src;
    float4 a = p[2 * j], b = p[2 * j + 1];
    f16x8 o;
    o[0] = (f16)a.x; o[1] = (f16)a.y; o[2] = (f16)a.z; o[3] = (f16)a.w;
    o[4] = (f16)b.x; o[5] = (f16)b.y; o[6] = (f16)b.z; o[7] = (f16)b.w;
    *(f16x8*)(dst + 8 * j) = o;
}

// ---------------------------------------------------------------- pipelined GEMM  C = A * B^T
// v6 (proven): BM=128 BN=256 BK=64, 8 waves, 3-stage LDS rotation (144KB),
// prefetch distance 2, counted vmcnt(6) + raw s_barrier (never drains mid-loop).
template <int MODE>
__global__ __launch_bounds__(512)
void gemm_pipe(const f16* __restrict__ A, const f16* __restrict__ Bm,
               const float* __restrict__ bias,
               f16* __restrict__ qo, f16* __restrict__ ko, f16* __restrict__ vto,
               float* __restrict__ Cf)
{
    constexpr int K = 1024, NT = 16;
    constexpr int N = (MODE == 0) ? 3072 : 1024;
    constexpr int NTN = N / 256;
    constexpr int NBLK = 64 * NTN;
    __shared__ __align__(16) f16 L[3][(128 + 256) * 64];
    const int tid = threadIdx.x, wave = tid >> 6, lane = tid & 63;
    const int lo = lane & 15, hi = lane >> 4;
    const int bid0 = blockIdx.x;
    const int bid = (bid0 & 7) * (NBLK / 8) + (bid0 >> 3);
    const int tm = bid / NTN, tn = bid % NTN;
    const long bm0 = (long)tm * 128, bn0 = (long)tn * 256;
    const int wr = (wave >> 2) * 64, wc = (wave & 3) * 64;

#define STAGE6(BUF, T)  do {                                                      \
    const long kk = (long)(T) * 64;                                               \
    _Pragma("unroll")                                                             \
    for (int j = 0; j < 2; ++j) {                                                 \
        const int c = j * 512 + tid;                                              \
        const int row = c >> 3, ch = c & 7;                                       \
        async_lds16(A + (bm0 + row) * K + kk + ((ch ^ (row & 7)) * 8),            \
                    &L[BUF][(j * 512 + wave * 64) * 8]);                          \
    }                                                                             \
    _Pragma("unroll")                                                             \
    for (int j = 0; j < 4; ++j) {                                                 \
        const int c = j * 512 + tid;                                              \
        const int row = c >> 3, ch = c & 7;                                       \
        async_lds16(Bm + (bn0 + row) * K + kk + ((ch ^ (row & 7)) * 8),           \
                    &L[BUF][8192 + (j * 512 + wave * 64) * 8]);                   \
    } } while (0)

    f32x4 acc[4][4] = {};

    auto tile = [&](auto bufc, int t) {
        constexpr int BUF = decltype(bufc)::v;
        constexpr int SBUF = (BUF + 2) % 3;
        if (t + 2 < NT) STAGE6(SBUF, t + 2);
        f16x8 af[2][4], bf[2][4];
#pragma unroll
        for (int kh = 0; kh < 2; ++kh) {
#pragma unroll
            for (int mi = 0; mi < 4; ++mi) {
                const int r = wr + mi * 16 + lo;
                af[kh][mi] = *(const f16x8*)&L[BUF][(r * 8 + ((kh * 4 + hi) ^ (r & 7))) * 8];
            }
#pragma unroll
            for (int ni = 0; ni < 4; ++ni) {
                const int r = wc + ni * 16 + lo;
                bf[kh][ni] = *(const f16x8*)&L[BUF][8192 + (r * 8 + ((kh * 4 + hi) ^ (r & 7))) * 8];
            }
        }
        __builtin_amdgcn_s_setprio(1);
#pragma unroll
        for (int kh = 0; kh < 2; ++kh)
#pragma unroll
            for (int mi = 0; mi < 4; ++mi)
#pragma unroll
                for (int ni = 0; ni < 4; ++ni)
                    acc[mi][ni] = __builtin_amdgcn_mfma_f32_16x16x32_f16(
                        af[kh][mi], bf[kh][ni], acc[mi][ni], 0, 0, 0);
        __builtin_amdgcn_s_setprio(0);
        if (t + 2 < NT) asm volatile("s_waitcnt vmcnt(6)" ::: "memory");
        else            asm volatile("s_waitcnt vmcnt(0)" ::: "memory");
        __builtin_amdgcn_sched_barrier(0);
        __builtin_amdgcn_s_barrier();
    };

    STAGE6(0, 0);
    STAGE6(1, 1);
    asm volatile("s_waitcnt vmcnt(6)" ::: "memory");
    __builtin_amdgcn_sched_barrier(0);
    __builtin_amdgcn_s_barrier();
    for (int t = 0; t < 15; t += 3) {
        tile(IC<0>{}, t);
        tile(IC<1>{}, t + 1);
        tile(IC<2>{}, t + 2);
    }
    tile(IC<0>{}, 15);
#undef STAGE6

    if (MODE == 1) {
#pragma unroll
        for (int mi = 0; mi < 4; ++mi)
#pragma unroll
            for (int ni = 0; ni < 4; ++ni)
#pragma unroll
                for (int j = 0; j < 4; ++j) {
                    const long r  = bm0 + wr + mi * 16 + 4 * hi + j;
                    const int  cn = (int)bn0 + wc + ni * 16 + lo;
                    Cf[r * N + cn] = acc[mi][ni][j] + bias[cn];
                }
        return;
    }

    const int which = (int)(bn0 >> 10);
    if (which < 2) {
#pragma unroll
        for (int mi = 0; mi < 4; ++mi)
#pragma unroll
            for (int ni = 0; ni < 4; ++ni)
#pragma unroll
                for (int j = 0; j < 4; ++j) {
                    const long r  = bm0 + wr + mi * 16 + 4 * hi + j;
                    const int  cn = (int)bn0 + wc + ni * 16 + lo;
                    const int  e = cn & 1023, h = e >> 6, d = e & 63;
                    const int  b = (int)(r >> 11), s = (int)(r & 2047);
                    const long bh = (long)b * H_ + h;
                    const f16 hv = (f16)(acc[mi][ni][j] + bias[cn]);
                    if (which == 0) qo[(bh * S_ + s) * HD_ + d] = hv;
                    else            ko[(bh * S_ + s) * HD_ + d] = hv;
                }
    } else {
        f16* T = ((f16*)L) + wave * 4096;
#pragma unroll
        for (int ni = 0; ni < 4; ++ni) {
            const int dl = ni * 16 + lo;
            const int dx = dl & 7;
#pragma unroll
            for (int mi = 0; mi < 4; ++mi)
#pragma unroll
                for (int j = 0; j < 4; ++j) {
                    const int sl = mi * 16 + 4 * hi + j;
                    const int cn = (int)bn0 + wc + ni * 16 + lo;
                    T[dl * 64 + ((((sl >> 3) ^ dx) << 3) | (sl & 7))] =
                        (f16)(acc[mi][ni][j] + bias[cn]);
                }
        }
        const int b = (int)(bm0 >> 11);
        const int sbase = (int)(bm0 & 2047) + wr;
        const int h = ((int)(bn0 & 1023) + wc) >> 6;
        const long vbase = (long)(b * H_ + h) * HD_;
#pragma unroll
        for (int it = 0; it < 8; ++it) {
            const int d = it * 8 + (lane >> 3);
            const int schunk = lane & 7;
            u32x4 val = *(const u32x4*)&T[d * 64 + ((schunk ^ (d & 7)) << 3)];
            *(u32x4*)&vto[(vbase + d) * S_ + sbase + schunk * 8] = val;
        }
    }
}

// ---------------------------------------------------------------- causal flash attention
// v11: fused strip processing. Per staged KV tile, strips A and B are computed
// in ONE interleaved body: QK shares each kf LDS read, PV shares each vf read
// (halves LDS reads + addressing), and the independent A/B chains double the
// per-wave ILP (we are capped at 2 waves/SIMD by the 512-block grid). Row-sum
// l now accumulated via ones-MFMA (lacc rows = q = oacc rows -> direct
// normalize, no dot2 chain, no epilogue shuffles). XCD-locality grid (64,8).
__global__ __launch_bounds__(256)
void attn_fwd(const f16* __restrict__ qb, const f16* __restrict__ kb,
              const f16* __restrict__ vtb, f16* __restrict__ ob)
{
    __shared__ __align__(16) f16 Ks[2][64 * 64];
    __shared__ __align__(16) f16 Vs[2][64 * 64];
    const int tid = threadIdx.x, wave = tid >> 6, lane = tid & 63;
    const int q32 = lane & 31, h2 = lane >> 5;
    const int bh = blockIdx.x;           // XCD = id%8 = bh%8
    const int qtA = blockIdx.y;          // 0..7
    const int qtB = 15 - qtA;
    const int qwA = qtA * 128 + wave * 32;
    const int qwB = qtB * 128 + wave * 32;
    const long krow0 = (long)bh * S_;
    const long vrow0 = (long)bh * HD_;

#define STAGE(BUF, KV)  do {                                                      \
    _Pragma("unroll")                                                             \
    for (int p = 0; p < 2; ++p) {                                                 \
        const int n = p * 256 + tid;                                              \
        const int base = (p * 256 + wave * 64) * 8;                               \
        async_lds16(kb  + (krow0 + (KV) + (n & 63)) * HD_ + (n >> 6) * 8, &Ks[BUF][base]); \
        async_lds16(vtb + (vrow0 + (n & 63)) * S_ + (KV) + (n >> 6) * 8, &Vs[BUF][base]);  \
    } } while (0)

    f16x8 qfA[4], qfB[4];
    const f16 sch = (f16)0.1803368801f;
#pragma unroll
    for (int kkq = 0; kkq < 4; ++kkq) {
        qfA[kkq] = *(const f16x8*)&qb[(krow0 + qwA + q32) * HD_ + kkq * 16 + h2 * 8];
        qfB[kkq] = *(const f16x8*)&qb[(krow0 + qwB + q32) * HD_ + kkq * 16 + h2 * 8];
#pragma unroll
        for (int e = 0; e < 8; ++e) { qfA[kkq][e] *= sch; qfB[kkq][e] *= sch; }
    }

    f16x8 ones8;
#pragma unroll
    for (int e = 0; e < 8; ++e) ones8[e] = (f16)1.0f;

    f32x16 oaccA[2] = {}, oaccB[2] = {};
    f32x16 laccA = {}, laccB = {};

    // one interleaved body for both strips; ACTA=0 when strip A is done.
    auto compute = [&](auto bufc, auto actc, int t) {
        constexpr int BUF  = decltype(bufc)::v;
        constexpr int ACTA = decltype(actc)::v;
        const int kv0 = t * 64;

        f32x16 scA[2] = {}, scB[2] = {};
        __builtin_amdgcn_s_setprio(1);
#pragma unroll
        for (int kkq = 0; kkq < 4; ++kkq)
#pragma unroll
            for (int ni = 0; ni < 2; ++ni) {
                f16x8 kf = *(const f16x8*)&Ks[BUF][(((kkq * 2 + h2) * 64) + ni * 32 + q32) * 8];
                scB[ni] = __builtin_amdgcn_mfma_f32_32x32x16_f16(kf, qfB[kkq], scB[ni], 0, 0, 0);
                if constexpr (ACTA)
                    scA[ni] = __builtin_amdgcn_mfma_f32_32x32x16_f16(kf, qfA[kkq], scA[ni], 0, 0, 0);
            }
        __builtin_amdgcn_s_setprio(0);

        // softmax: p = exp2(s) (raw v_exp_f32); mask only on diagonal tiles
        const bool maskB = (kv0 + 63) > qwB;
        const int qgB = qwB + q32;
#pragma unroll
        for (int ni = 0; ni < 2; ++ni)
#pragma unroll
            for (int r = 0; r < 16; ++r) {
                float p = __builtin_amdgcn_exp2f(scB[ni][r]);
                const int kvg = kv0 + ni * 32 + (r & 3) + 8 * (r >> 2) + 4 * h2;
                if (maskB && kvg > qgB) p = 0.0f;
                scB[ni][r] = p;
            }
        if constexpr (ACTA) {
            const bool maskA = (kv0 + 63) > qwA;
            const int qgA = qwA + q32;
#pragma unroll
            for (int ni = 0; ni < 2; ++ni)
#pragma unroll
                for (int r = 0; r < 16; ++r) {
                    float p = __builtin_amdgcn_exp2f(scA[ni][r]);
                    const int kvg = kv0 + ni * 32 + (r & 3) + 8 * (r >> 2) + 4 * h2;
                    if (maskA && kvg > qgA) p = 0.0f;
                    scA[ni][r] = p;
                }
        }

        // pack + PV for both strips, sharing vf reads; l via ones-MFMA
        __builtin_amdgcn_s_setprio(1);
#pragma unroll
        for (int ni = 0; ni < 2; ++ni) {
            uint32_t uB[8], uA[8];
#pragma unroll
            for (int m = 0; m < 8; ++m) {
                uB[m] = __builtin_bit_cast(uint32_t,
                        __builtin_amdgcn_cvt_pkrtz(scB[ni][2 * m], scB[ni][2 * m + 1]));
                if constexpr (ACTA)
                    uA[m] = __builtin_bit_cast(uint32_t,
                            __builtin_amdgcn_cvt_pkrtz(scA[ni][2 * m], scA[ni][2 * m + 1]));
            }
#pragma unroll
            for (int kkv = 0; kkv < 2; ++kkv) {
                auto sA1 = __builtin_amdgcn_permlane32_swap(uB[4 * kkv + 0], uB[4 * kkv + 2], false, false);
                auto sB1 = __builtin_amdgcn_permlane32_swap(uB[4 * kkv + 1], uB[4 * kkv + 3], false, false);
                u32x4 uvB = { (uint32_t)sA1[0], (uint32_t)sB1[0], (uint32_t)sA1[1], (uint32_t)sB1[1] };
                f16x8 pfB = __builtin_bit_cast(f16x8, uvB);
                laccB = __builtin_amdgcn_mfma_f32_32x32x16_f16(pfB, ones8, laccB, 0, 0, 0);
                f16x8 pfA;
                if constexpr (ACTA) {
                    auto sA2 = __builtin_amdgcn_permlane32_swap(uA[4 * kkv + 0], uA[4 * kkv + 2], false, false);
                    auto sB2 = __builtin_amdgcn_permlane32_swap(uA[4 * kkv + 1], uA[4 * kkv + 3], false, false);
                    u32x4 uvA = { (uint32_t)sA2[0], (uint32_t)sB2[0], (uint32_t)sA2[1], (uint32_t)sB2[1] };
                    pfA = __builtin_bit_cast(f16x8, uvA);
                    laccA = __builtin_amdgcn_mfma_f32_32x32x16_f16(pfA, ones8, laccA, 0, 0, 0);
                }
                const int kg = ni * 2 + kkv;
#pragma unroll
                for (int dh = 0; dh < 2; ++dh) {
                    f16x8 vf = *(const f16x8*)&Vs[BUF][(((kg * 2 + h2) * 64) + dh * 32 + q32) * 8];
                    oaccB[dh] = __builtin_amdgcn_mfma_f32_32x32x16_f16(pfB, vf, oaccB[dh], 0, 0, 0);
                    if constexpr (ACTA)
                        oaccA[dh] = __builtin_amdgcn_mfma_f32_32x32x16_f16(pfA, vf, oaccA[dh], 0, 0, 0);
                }
            }
        }
        __builtin_amdgcn_s_setprio(0);
    };

    const int ntB = 2 * (qtB + 1);
    STAGE(0, 0);
    __syncthreads();
    for (int t = 0; t < ntB; t += 2) {
        STAGE(1, (t + 1) * 64);
        if (t * 64 <= qwA + 31) compute(IC<0>{}, IC<1>{}, t);
        else                    compute(IC<0>{}, IC<0>{}, t);
        __syncthreads();
        if (t + 2 < ntB) STAGE(0, (t + 2) * 64);
        if ((t + 1) * 64 <= qwA + 31) compute(IC<1>{}, IC<1>{}, t + 1);
        else                          compute(IC<1>{}, IC<0>{}, t + 1);
        __syncthreads();
    }
#undef STAGE

    // normalize + write both strips: lacc rows = oacc rows -> direct reciprocal
    const int b = bh >> 4, h = bh & 15;
#pragma unroll
    for (int r = 0; r < 16; ++r) {
        const int crow = (r & 3) + 8 * (r >> 2) + 4 * h2;
        const float irA = 1.0f / laccA[r];
        const float irB = 1.0f / laccB[r];
#pragma unroll
        for (int dh = 0; dh < 2; ++dh) {
            ob[((long)b * S_ + qwA + crow) * E_ + h * HD_ + dh * 32 + q32] = (f16)(oaccA[dh][r] * irA);
            ob[((long)b * S_ + qwB + crow) * E_ + h * HD_ + dh * 32 + q32] = (f16)(oaccB[dh][r] * irB);
        }
    }
}

// ---------------------------------------------------------------- launch
extern "C" void kernel_launch(void* const* d_in, const int* in_sizes, int n_in,
                              void* d_out, int out_size, void* d_ws, size_t ws_size,
                              hipStream_t stream)
{
    (void)in_sizes; (void)n_in; (void)out_size; (void)ws_size;
    const float* x  = (const float*)d_in[0];
    const float* w1 = (const float*)d_in[1];
    const float* b1 = (const float*)d_in[2];
    const float* w2 = (const float*)d_in[3];
    const float* b2 = (const float*)d_in[4];
    float* out = (float*)d_out;

    char* ws = (char*)d_ws;
    f16* xb  = (f16*)ws;  ws += (size_t)8192 * 1024 * 2;
    f16* w1b = (f16*)ws;  ws += (size_t)3072 * 1024 * 2;
    f16* w2b = (f16*)ws;  ws += (size_t)1024 * 1024 * 2;
    f16* qb  = (f16*)ws;  ws += (size_t)BH_ * S_ * HD_ * 2;
    f16* kb  = (f16*)ws;  ws += (size_t)BH_ * S_ * HD_ * 2;
    f16* vtb = (f16*)ws;  ws += (size_t)BH_ * S_ * HD_ * 2;
    f16* ao  = (f16*)ws;  ws += (size_t)8192 * 1024 * 2;

    cvt3<<<dim3(6144), dim3(256), 0, stream>>>(x, w1, w2, xb, w1b, w2b);

    gemm_pipe<0><<<dim3(768), dim3(512), 0, stream>>>(xb, w1b, b1, qb, kb, vtb, nullptr);

    attn_fwd<<<dim3(64, 8), dim3(256), 0, stream>>>(qb, kb, vtb, ao);

    gemm_pipe<1><<<dim3(256), dim3(512), 0, stream>>>(ao, w2b, b2, nullptr, nullptr, nullptr, out);
}

// Round 18
// 148.533 us; speedup vs baseline: 1.1802x; 1.1802x over previous
//
#include <hip/hip_runtime.h>
#include <stdint.h>

typedef _Float16 f16;
typedef _Float16 f16x2 __attribute__((ext_vector_type(2)));
typedef _Float16 f16x8 __attribute__((ext_vector_type(8)));
typedef float f32x4 __attribute__((ext_vector_type(4)));
typedef float f32x16 __attribute__((ext_vector_type(16)));
typedef uint32_t u32x4 __attribute__((ext_vector_type(4)));

#define B_   4
#define S_   2048
#define E_   1024
#define H_   16
#define HD_  64
#define BH_  (B_ * H_)

template <int N> struct IC { static constexpr int v = N; };

// ---------------------------------------------------------------- helpers
__device__ __forceinline__ void async_lds16(const void* g, void* l) {
    __builtin_amdgcn_global_load_lds(
        (__attribute__((address_space(1))) void*)(uintptr_t)g,
        (__attribute__((address_space(3))) void*)(uint32_t)(uintptr_t)l,
        16, 0, 0);
}

// ---------------------------------------------------------------- fused fp32 -> fp16 (x, w1, w2)
__global__ __launch_bounds__(256)
void cvt3(const float* __restrict__ x, const float* __restrict__ w1,
          const float* __restrict__ w2, f16* __restrict__ xb,
          f16* __restrict__ w1b, f16* __restrict__ w2b)
{
    const long i = (long)blockIdx.x * 256 + threadIdx.x;   // 8-elem chunk id
    const float* src; f16* dst; long j;
    if (i < 1048576)      { src = x;  dst = xb;  j = i; }
    else if (i < 1441792) { src = w1; dst = w1b; j = i - 1048576; }
    else                  { src = w2; dst = w2b; j = i - 1441792; }
    const float4* p = (const float4*)src;
    float4 a = p[2 * j], b = p[2 * j + 1];
    f16x8 o;
    o[0] = (f16)a.x; o[1] = (f16)a.y; o[2] = (f16)a.z; o[3] = (f16)a.w;
    o[4] = (f16)b.x; o[5] = (f16)b.y; o[6] = (f16)b.z; o[7] = (f16)b.w;
    *(f16x8*)(dst + 8 * j) = o;
}

// ---------------------------------------------------------------- pipelined GEMM  C = A * B^T
// v6 (proven): BM=128 BN=256 BK=64, 8 waves, 3-stage LDS rotation (144KB),
// prefetch distance 2, counted vmcnt(6) + raw s_barrier (never drains mid-loop).
// MODE 0: QKV (N=3072), scatter epilogue (q/k + vT LDS-transpose).
// MODE 1: out-proj (N=1024), fp32 C + bias epilogue.
template <int MODE>
__global__ __launch_bounds__(512)
void gemm_pipe(const f16* __restrict__ A, const f16* __restrict__ Bm,
               const float* __restrict__ bias,
               f16* __restrict__ qo, f16* __restrict__ ko, f16* __restrict__ vto,
               float* __restrict__ Cf)
{
    constexpr int K = 1024, NT = 16;
    constexpr int N = (MODE == 0) ? 3072 : 1024;
    constexpr int NTN = N / 256;
    constexpr int NBLK = 64 * NTN;
    __shared__ __align__(16) f16 L[3][(128 + 256) * 64];
    const int tid = threadIdx.x, wave = tid >> 6, lane = tid & 63;
    const int lo = lane & 15, hi = lane >> 4;
    const int bid0 = blockIdx.x;
    const int bid = (bid0 & 7) * (NBLK / 8) + (bid0 >> 3);   // XCD swizzle (NBLK%8==0)
    const int tm = bid / NTN, tn = bid % NTN;
    const long bm0 = (long)tm * 128, bn0 = (long)tn * 256;
    const int wr = (wave >> 2) * 64, wc = (wave & 3) * 64;

#define STAGE6(BUF, T)  do {                                                      \
    const long kk = (long)(T) * 64;                                               \
    _Pragma("unroll")                                                             \
    for (int j = 0; j < 2; ++j) {                                                 \
        const int c = j * 512 + tid;                                              \
        const int row = c >> 3, ch = c & 7;                                       \
        async_lds16(A + (bm0 + row) * K + kk + ((ch ^ (row & 7)) * 8),            \
                    &L[BUF][(j * 512 + wave * 64) * 8]);                          \
    }                                                                             \
    _Pragma("unroll")                                                             \
    for (int j = 0; j < 4; ++j) {                                                 \
        const int c = j * 512 + tid;                                              \
        const int row = c >> 3, ch = c & 7;                                       \
        async_lds16(Bm + (bn0 + row) * K + kk + ((ch ^ (row & 7)) * 8),           \
                    &L[BUF][8192 + (j * 512 + wave * 64) * 8]);                   \
    } } while (0)

    f32x4 acc[4][4] = {};

    auto tile = [&](auto bufc, int t) {
        constexpr int BUF = decltype(bufc)::v;
        constexpr int SBUF = (BUF + 2) % 3;
        if (t + 2 < NT) STAGE6(SBUF, t + 2);
        f16x8 af[2][4], bf[2][4];
#pragma unroll
        for (int kh = 0; kh < 2; ++kh) {
#pragma unroll
            for (int mi = 0; mi < 4; ++mi) {
                const int r = wr + mi * 16 + lo;
                af[kh][mi] = *(const f16x8*)&L[BUF][(r * 8 + ((kh * 4 + hi) ^ (r & 7))) * 8];
            }
#pragma unroll
            for (int ni = 0; ni < 4; ++ni) {
                const int r = wc + ni * 16 + lo;
                bf[kh][ni] = *(const f16x8*)&L[BUF][8192 + (r * 8 + ((kh * 4 + hi) ^ (r & 7))) * 8];
            }
        }
        __builtin_amdgcn_s_setprio(1);
#pragma unroll
        for (int kh = 0; kh < 2; ++kh)
#pragma unroll
            for (int mi = 0; mi < 4; ++mi)
#pragma unroll
                for (int ni = 0; ni < 4; ++ni)
                    acc[mi][ni] = __builtin_amdgcn_mfma_f32_16x16x32_f16(
                        af[kh][mi], bf[kh][ni], acc[mi][ni], 0, 0, 0);
        __builtin_amdgcn_s_setprio(0);
        if (t + 2 < NT) asm volatile("s_waitcnt vmcnt(6)" ::: "memory");
        else            asm volatile("s_waitcnt vmcnt(0)" ::: "memory");
        __builtin_amdgcn_sched_barrier(0);
        __builtin_amdgcn_s_barrier();
    };

    STAGE6(0, 0);
    STAGE6(1, 1);
    asm volatile("s_waitcnt vmcnt(6)" ::: "memory");
    __builtin_amdgcn_sched_barrier(0);
    __builtin_amdgcn_s_barrier();
    for (int t = 0; t < 15; t += 3) {
        tile(IC<0>{}, t);
        tile(IC<1>{}, t + 1);
        tile(IC<2>{}, t + 2);
    }
    tile(IC<0>{}, 15);
#undef STAGE6

    if (MODE == 1) {
#pragma unroll
        for (int mi = 0; mi < 4; ++mi)
#pragma unroll
            for (int ni = 0; ni < 4; ++ni)
#pragma unroll
                for (int j = 0; j < 4; ++j) {
                    const long r  = bm0 + wr + mi * 16 + 4 * hi + j;
                    const int  cn = (int)bn0 + wc + ni * 16 + lo;
                    Cf[r * N + cn] = acc[mi][ni][j] + bias[cn];
                }
        return;
    }

    const int which = (int)(bn0 >> 10);
    if (which < 2) {
#pragma unroll
        for (int mi = 0; mi < 4; ++mi)
#pragma unroll
            for (int ni = 0; ni < 4; ++ni)
#pragma unroll
                for (int j = 0; j < 4; ++j) {
                    const long r  = bm0 + wr + mi * 16 + 4 * hi + j;
                    const int  cn = (int)bn0 + wc + ni * 16 + lo;
                    const int  e = cn & 1023, h = e >> 6, d = e & 63;
                    const int  b = (int)(r >> 11), s = (int)(r & 2047);
                    const long bh = (long)b * H_ + h;
                    const f16 hv = (f16)(acc[mi][ni][j] + bias[cn]);
                    if (which == 0) qo[(bh * S_ + s) * HD_ + d] = hv;
                    else            ko[(bh * S_ + s) * HD_ + d] = hv;
                }
    } else {
        f16* T = ((f16*)L) + wave * 4096;
#pragma unroll
        for (int ni = 0; ni < 4; ++ni) {
            const int dl = ni * 16 + lo;
            const int dx = dl & 7;
#pragma unroll
            for (int mi = 0; mi < 4; ++mi)
#pragma unroll
                for (int j = 0; j < 4; ++j) {
                    const int sl = mi * 16 + 4 * hi + j;
                    const int cn = (int)bn0 + wc + ni * 16 + lo;
                    T[dl * 64 + ((((sl >> 3) ^ dx) << 3) | (sl & 7))] =
                        (f16)(acc[mi][ni][j] + bias[cn]);
                }
        }
        const int b = (int)(bm0 >> 11);
        const int sbase = (int)(bm0 & 2047) + wr;
        const int h = ((int)(bn0 & 1023) + wc) >> 6;
        const long vbase = (long)(b * H_ + h) * HD_;
#pragma unroll
        for (int it = 0; it < 8; ++it) {
            const int d = it * 8 + (lane >> 3);
            const int schunk = lane & 7;
            u32x4 val = *(const u32x4*)&T[d * 64 + ((schunk ^ (d & 7)) << 3)];
            *(u32x4*)&vto[(vbase + d) * S_ + sbase + schunk * 8] = val;
        }
    }
}

// ---------------------------------------------------------------- causal flash attention
// v10 (proven 67.7us): 32x32 swapped QK, in-register P via cvt_pkrtz +
// permlane32_swap, chunk-major LDS, static ping-pong, strip pairing
// (qtA, 15-qtA -> exactly 34 tile-units/block), raw v_exp_f32 softmax with
// scale folded into Q, dot2 row-sums, XCD-locality grid (64,8): id%8 = bh%8
// so the 8 strip-blocks of a bh share one XCD L2 (FETCH 110 -> 24.7 MB).
__global__ __launch_bounds__(256)
void attn_fwd(const f16* __restrict__ qb, const f16* __restrict__ kb,
              const f16* __restrict__ vtb, f16* __restrict__ ob)
{
    __shared__ __align__(16) f16 Ks[2][64 * 64];
    __shared__ __align__(16) f16 Vs[2][64 * 64];
    const int tid = threadIdx.x, wave = tid >> 6, lane = tid & 63;
    const int q32 = lane & 31, h2 = lane >> 5;
    const int bh = blockIdx.x;           // XCD = id%8 = bh%8
    const int qtA = blockIdx.y;          // 0..7
    const int qtB = 15 - qtA;
    const int qwA = qtA * 128 + wave * 32;
    const int qwB = qtB * 128 + wave * 32;
    const long krow0 = (long)bh * S_;
    const long vrow0 = (long)bh * HD_;

#define STAGE(BUF, KV)  do {                                                      \
    _Pragma("unroll")                                                             \
    for (int p = 0; p < 2; ++p) {                                                 \
        const int n = p * 256 + tid;                                              \
        const int base = (p * 256 + wave * 64) * 8;                               \
        async_lds16(kb  + (krow0 + (KV) + (n & 63)) * HD_ + (n >> 6) * 8, &Ks[BUF][base]); \
        async_lds16(vtb + (vrow0 + (n & 63)) * S_ + (KV) + (n >> 6) * 8, &Vs[BUF][base]);  \
    } } while (0)

    f16x8 qfA[4], qfB[4];
    const f16 sch = (f16)0.1803368801f;
#pragma unroll
    for (int kkq = 0; kkq < 4; ++kkq) {
        qfA[kkq] = *(const f16x8*)&qb[(krow0 + qwA + q32) * HD_ + kkq * 16 + h2 * 8];
        qfB[kkq] = *(const f16x8*)&qb[(krow0 + qwB + q32) * HD_ + kkq * 16 + h2 * 8];
#pragma unroll
        for (int e = 0; e < 8; ++e) { qfA[kkq][e] *= sch; qfB[kkq][e] *= sch; }
    }

    f32x16 oaccA[2] = {}, oaccB[2] = {};
    float lA = 0.f, lB = 0.f;
    const f16x2 ones2 = { (f16)1.0f, (f16)1.0f };

    auto computeS = [&](auto bufc, auto spc, int t) {
        constexpr int BUF = decltype(bufc)::v;
        constexpr int SP  = decltype(spc)::v;
        const int qw = SP ? qwB : qwA;
        const f16x8* qf = SP ? qfB : qfA;
        f32x16* oacc = SP ? oaccB : oaccA;
        float& l_part = SP ? lB : lA;
        const int kv0 = t * 64;
        if (kv0 > qw + 31) return;
        const int qg = qw + q32;

        f32x16 sc[2] = {};
        __builtin_amdgcn_s_setprio(1);
#pragma unroll
        for (int kkq = 0; kkq < 4; ++kkq)
#pragma unroll
            for (int ni = 0; ni < 2; ++ni) {
                f16x8 kf = *(const f16x8*)&Ks[BUF][(((kkq * 2 + h2) * 64) + ni * 32 + q32) * 8];
                sc[ni] = __builtin_amdgcn_mfma_f32_32x32x16_f16(kf, qf[kkq], sc[ni], 0, 0, 0);
            }
        __builtin_amdgcn_s_setprio(0);

        const bool maskp = (kv0 + 63) > qw;
#pragma unroll
        for (int ni = 0; ni < 2; ++ni)
#pragma unroll
            for (int r = 0; r < 16; ++r) {
                float p = __builtin_amdgcn_exp2f(sc[ni][r]);
                const int kvg = kv0 + ni * 32 + (r & 3) + 8 * (r >> 2) + 4 * h2;
                if (maskp && kvg > qg) p = 0.0f;
                sc[ni][r] = p;
            }

        __builtin_amdgcn_s_setprio(1);
#pragma unroll
        for (int ni = 0; ni < 2; ++ni) {
            uint32_t u[8];
#pragma unroll
            for (int m = 0; m < 8; ++m) {
                auto hp = __builtin_amdgcn_cvt_pkrtz(sc[ni][2 * m], sc[ni][2 * m + 1]);
                u[m] = __builtin_bit_cast(uint32_t, hp);
                l_part = __builtin_amdgcn_fdot2(__builtin_bit_cast(f16x2, u[m]), ones2, l_part, false);
            }
#pragma unroll
            for (int kkv = 0; kkv < 2; ++kkv) {
                auto sA = __builtin_amdgcn_permlane32_swap(u[4 * kkv + 0], u[4 * kkv + 2], false, false);
                auto sB = __builtin_amdgcn_permlane32_swap(u[4 * kkv + 1], u[4 * kkv + 3], false, false);
                u32x4 uv = { (uint32_t)sA[0], (uint32_t)sB[0], (uint32_t)sA[1], (uint32_t)sB[1] };
                f16x8 pf = __builtin_bit_cast(f16x8, uv);
                const int kg = ni * 2 + kkv;
#pragma unroll
                for (int dh = 0; dh < 2; ++dh) {
                    f16x8 vf = *(const f16x8*)&Vs[BUF][(((kg * 2 + h2) * 64) + dh * 32 + q32) * 8];
                    oacc[dh] = __builtin_amdgcn_mfma_f32_32x32x16_f16(pf, vf, oacc[dh], 0, 0, 0);
                }
            }
        }
        __builtin_amdgcn_s_setprio(0);
    };

    const int ntB = 2 * (qtB + 1);
    STAGE(0, 0);
    __syncthreads();
    for (int t = 0; t < ntB; t += 2) {
        STAGE(1, (t + 1) * 64);
        computeS(IC<0>{}, IC<0>{}, t);
        computeS(IC<0>{}, IC<1>{}, t);
        __syncthreads();
        if (t + 2 < ntB) STAGE(0, (t + 2) * 64);
        computeS(IC<1>{}, IC<0>{}, t + 1);
        computeS(IC<1>{}, IC<1>{}, t + 1);
        __syncthreads();
    }
#undef STAGE

    const int b = bh >> 4, h = bh & 15;
    const float invA = 1.0f / (lA + __shfl_xor(lA, 32));
    const float invB = 1.0f / (lB + __shfl_xor(lB, 32));
#pragma unroll
    for (int r = 0; r < 16; ++r) {
        const int crow = (r & 3) + 8 * (r >> 2) + 4 * h2;
        const float irA = __shfl(invA, crow);
        const float irB = __shfl(invB, crow);
#pragma unroll
        for (int dh = 0; dh < 2; ++dh) {
            ob[((long)b * S_ + qwA + crow) * E_ + h * HD_ + dh * 32 + q32] = (f16)(oaccA[dh][r] * irA);
            ob[((long)b * S_ + qwB + crow) * E_ + h * HD_ + dh * 32 + q32] = (f16)(oaccB[dh][r] * irB);
        }
    }
}

// ---------------------------------------------------------------- launch
extern "C" void kernel_launch(void* const* d_in, const int* in_sizes, int n_in,
                              void* d_out, int out_size, void* d_ws, size_t ws_size,
                              hipStream_t stream)
{
    (void)in_sizes; (void)n_in; (void)out_size; (void)ws_size;
    const float* x  = (const float*)d_in[0];
    const float* w1 = (const float*)d_in[1];
    const float* b1 = (const float*)d_in[2];
    const float* w2 = (const float*)d_in[3];
    const float* b2 = (const float*)d_in[4];
    float* out = (float*)d_out;

    char* ws = (char*)d_ws;
    f16* xb  = (f16*)ws;  ws += (size_t)8192 * 1024 * 2;
    f16* w1b = (f16*)ws;  ws += (size_t)3072 * 1024 * 2;
    f16* w2b = (f16*)ws;  ws += (size_t)1024 * 1024 * 2;
    f16* qb  = (f16*)ws;  ws += (size_t)BH_ * S_ * HD_ * 2;
    f16* kb  = (f16*)ws;  ws += (size_t)BH_ * S_ * HD_ * 2;
    f16* vtb = (f16*)ws;  ws += (size_t)BH_ * S_ * HD_ * 2;
    f16* ao  = (f16*)ws;  ws += (size_t)8192 * 1024 * 2;

    cvt3<<<dim3(6144), dim3(256), 0, stream>>>(x, w1, w2, xb, w1b, w2b);

    gemm_pipe<0><<<dim3(768), dim3(512), 0, stream>>>(xb, w1b, b1, qb, kb, vtb, nullptr);

    attn_fwd<<<dim3(64, 8), dim3(256), 0, stream>>>(qb, kb, vtb, ao);

    gemm_pipe<1><<<dim3(256), dim3(512), 0, stream>>>(ao, w2b, b2, nullptr, nullptr, nullptr, out);
}